// Round 1
// baseline (1123.674 us; speedup 1.0000x reference)
//
#include <hip/hip_runtime.h>
#include <hip/hip_bf16.h>
#include <stdint.h>

// Grid geometry (fixed by the problem)
#define D_ 32
#define H_ 128
#define W_ 128
#define NCIN 16
#define NCOUT 32
#define NVOX 200000
#define NB 4
// Padded dense grid: halo of 2 on every side so all 5x5x5 reads are in-bounds.
#define PD (D_ + 4)
#define PH (H_ + 4)
#define PW (W_ + 4)

__device__ __forceinline__ size_t vox_off(int b, int z, int y, int x) {
    // element offset (in bf16 units / NCIN-channel groups) into padded dense
    return ((((size_t)b * PD + (z + 2)) * PH + (y + 2)) * PW + (x + 2)) * NCIN;
}

// ---------------------------------------------------------------------------
// Combined 5x5x5 kernel, one variant per boundary class (27 classes).
// Wc[cls][dz][dy][dx][ci][cf] = sum over k1+k2 = delta+2 (per axis), with k2
// restricted so the intermediate position q = p + k2 - 1 stays in-bounds for
// that class (low edge: k2>=1, high edge: k2<=1). This reproduces conv2's
// SAME-padding zeroing of h at out-of-bounds q. The mask in the reference is
// provably a no-op for outputs gathered at active voxels.
// ---------------------------------------------------------------------------
__global__ void wc_kernel(const float* __restrict__ W1, const float* __restrict__ W2,
                          float* __restrict__ Wc) {
    int blk = blockIdx.x;              // cls*125 + d
    int cls = blk / 125, d = blk % 125;
    int cz = cls / 9, cy = (cls / 3) % 3, cx = cls % 3;
    int sz = d / 25, sy = (d / 5) % 5, sx = d % 5;   // delta+2 per axis, 0..4
    int t = threadIdx.x;
    int ci = t >> 4, cf = t & 15;
    float acc = 0.f;
    for (int k1z = 0; k1z < 3; ++k1z) {
        int k2z = sz - k1z;
        if (k2z < 0 || k2z > 2) continue;
        if ((cz == 0 && k2z == 0) || (cz == 2 && k2z == 2)) continue;
        for (int k1y = 0; k1y < 3; ++k1y) {
            int k2y = sy - k1y;
            if (k2y < 0 || k2y > 2) continue;
            if ((cy == 0 && k2y == 0) || (cy == 2 && k2y == 2)) continue;
            for (int k1x = 0; k1x < 3; ++k1x) {
                int k2x = sx - k1x;
                if (k2x < 0 || k2x > 2) continue;
                if ((cx == 0 && k2x == 0) || (cx == 2 && k2x == 2)) continue;
                const float* w1 = W1 + ((k1z*3 + k1y)*3 + k1x) * (NCIN*NCOUT) + ci * NCOUT;
                const float* w2 = W2 + ((k2z*3 + k2y)*3 + k2x) * (NCOUT*NCIN) + cf;
                #pragma unroll
                for (int cm = 0; cm < NCOUT; ++cm)
                    acc = fmaf(w1[cm], w2[cm * NCIN], acc);
            }
        }
    }
    Wc[(size_t)blk * 256 + t] = acc;
}

// ---------------------------------------------------------------------------
// Scatter features into padded dense grid (coords are unique -> plain stores).
// ---------------------------------------------------------------------------
__global__ void scatter_kernel(const float* __restrict__ feats, const int* __restrict__ coors,
                               __hip_bfloat16* __restrict__ dense) {
    int t = blockIdx.x * blockDim.x + threadIdx.x;
    if (t >= NVOX * NCIN) return;
    int v = t >> 4, c = t & 15;
    int b = coors[v*4+0], z = coors[v*4+1], y = coors[v*4+2], x = coors[v*4+3];
    dense[vox_off(b, z, y, x) + c] = __float2bfloat16(feats[t]);
}

// ---------------------------------------------------------------------------
// Per active voxel: out[v][cf] = sum over 125 neighbors of Wc_cls[delta]·dense.
// 2 threads per voxel, 8 output channels each.
// ---------------------------------------------------------------------------
__global__ void __launch_bounds__(256) out_kernel(
        const int* __restrict__ coors, const __hip_bfloat16* __restrict__ dense,
        const float* __restrict__ Wc, float* __restrict__ out) {
    int t = blockIdx.x * blockDim.x + threadIdx.x;
    int v = t >> 1;
    if (v >= NVOX) return;
    int half = t & 1;
    int b = coors[v*4+0], z = coors[v*4+1], y = coors[v*4+2], x = coors[v*4+3];
    int cz = (z == 0) ? 0 : ((z == D_-1) ? 2 : 1);
    int cy = (y == 0) ? 0 : ((y == H_-1) ? 2 : 1);
    int cx = (x == 0) ? 0 : ((x == W_-1) ? 2 : 1);
    int cls = (cz*3 + cy)*3 + cx;
    const float* wcls = Wc + (size_t)cls * (125*256) + half * 8;

    float acc[8];
    #pragma unroll
    for (int i = 0; i < 8; ++i) acc[i] = 0.f;

    for (int dz = 0; dz < 5; ++dz) {
        for (int dy = 0; dy < 5; ++dy) {
            const __hip_bfloat16* rowp = dense + vox_off(b, z + dz - 2, y + dy - 2, x - 2);
            const float* wrow = wcls + (dz*5 + dy) * 5 * 256;
            #pragma unroll
            for (int dx = 0; dx < 5; ++dx) {
                const uint4* p = (const uint4*)(rowp + dx * NCIN);
                uint4 u0 = p[0];
                uint4 u1 = p[1];
                uint32_t uu0 = u0.x, uu1 = u0.y, uu2 = u0.z, uu3 = u0.w;
                uint32_t uu4 = u1.x, uu5 = u1.y, uu6 = u1.z, uu7 = u1.w;
                float xv[16];
                #pragma unroll
                for (int j = 0; j < 8; ++j) {
                    uint32_t u = (j==0)?uu0:(j==1)?uu1:(j==2)?uu2:(j==3)?uu3:
                                 (j==4)?uu4:(j==5)?uu5:(j==6)?uu6:uu7;
                    union { uint32_t i; float f; } lo, hi;
                    lo.i = u << 16;
                    hi.i = u & 0xffff0000u;
                    xv[2*j]   = lo.f;
                    xv[2*j+1] = hi.f;
                }
                const float* w = wrow + dx * 256;
                #pragma unroll
                for (int ci = 0; ci < 16; ++ci) {
                    float vv = xv[ci];
                    const float4 wa = *(const float4*)(w + ci*16);
                    const float4 wb = *(const float4*)(w + ci*16 + 4);
                    acc[0] = fmaf(vv, wa.x, acc[0]);
                    acc[1] = fmaf(vv, wa.y, acc[1]);
                    acc[2] = fmaf(vv, wa.z, acc[2]);
                    acc[3] = fmaf(vv, wa.w, acc[3]);
                    acc[4] = fmaf(vv, wb.x, acc[4]);
                    acc[5] = fmaf(vv, wb.y, acc[5]);
                    acc[6] = fmaf(vv, wb.z, acc[6]);
                    acc[7] = fmaf(vv, wb.w, acc[7]);
                }
            }
        }
    }
    float4* o = (float4*)(out + (size_t)v * 16 + half * 8);
    o[0] = make_float4(acc[0], acc[1], acc[2], acc[3]);
    o[1] = make_float4(acc[4], acc[5], acc[6], acc[7]);
}

extern "C" void kernel_launch(void* const* d_in, const int* in_sizes, int n_in,
                              void* d_out, int out_size, void* d_ws, size_t ws_size,
                              hipStream_t stream) {
    const float* features = (const float*)d_in[0];
    const int*   coors    = (const int*)d_in[1];
    const float* W1       = (const float*)d_in[2];
    const float* W2       = (const float*)d_in[3];
    float* out = (float*)d_out;

    const size_t dense_elems = (size_t)NB * PD * PH * PW * NCIN;   // 40,144,896
    const size_t dense_bytes = dense_elems * sizeof(__hip_bfloat16); // ~80.3 MB
    __hip_bfloat16* dense = (__hip_bfloat16*)d_ws;
    float* Wc = (float*)((char*)d_ws + ((dense_bytes + 255) / 256) * 256); // +3.5 MB

    // ws is re-poisoned before every launch: must zero the dense grid each call.
    hipMemsetAsync(dense, 0, dense_bytes, stream);

    wc_kernel<<<27 * 125, 256, 0, stream>>>(W1, W2, Wc);
    scatter_kernel<<<(NVOX * NCIN + 255) / 256, 256, 0, stream>>>(features, coors, dense);
    out_kernel<<<(NVOX * 2 + 255) / 256, 256, 0, stream>>>(coors, dense, Wc, out);
}

// Round 2
// 388.226 us; speedup vs baseline: 2.8944x; 2.8944x over previous
//
#include <hip/hip_runtime.h>
#include <hip/hip_bf16.h>
#include <stdint.h>

#define D_ 32
#define H_ 128
#define W_ 128
#define NCIN 16
#define NCOUT 32
#define NVOX 200000
#define NB 4
#define PD (D_ + 4)
#define PH (H_ + 4)
#define PW (W_ + 4)

// spatial tiles for locality buckets
#define TZ 8
#define TY 16
#define TX 8
#define NTZ (D_ / TZ)                  // 4
#define NTY (H_ / TY)                  // 8
#define NTX (W_ / TX)                  // 16
#define NTILES (NB * NTZ * NTY * NTX)  // 2048
#define NKEY (NTILES * 27)             // 55296

typedef __attribute__((ext_vector_type(8))) short bf16x8;
typedef __attribute__((ext_vector_type(4))) float f32x4;

__device__ __forceinline__ unsigned int vox_off(int b, int z, int y, int x) {
    return ((((unsigned)b * PD + (z + 2)) * PH + (y + 2)) * PW + (x + 2)) * NCIN;
}
__device__ __forceinline__ int cls_of(int z, int y, int x) {
    int cz = (z == 0) ? 0 : ((z == D_ - 1) ? 2 : 1);
    int cy = (y == 0) ? 0 : ((y == H_ - 1) ? 2 : 1);
    int cx = (x == 0) ? 0 : ((x == W_ - 1) ? 2 : 1);
    return (cz * 3 + cy) * 3 + cx;
}
__device__ __forceinline__ int tile_of(int b, int z, int y, int x) {
    return ((b * NTZ + (z / TZ)) * NTY + (y / TY)) * NTX + (x / TX);
}

// ---------------------------------------------------------------------------
// Combined 5x5x5 weights for all 27 boundary classes, written directly in the
// B-fragment layout of v_mfma_f32_16x16x32_bf16:
//   WcB[cls][chunk c][lane][j]  (8 bf16 per lane = one 16B load per MFMA)
//   k = (lane>>4)*8 + j;  local_delta = k>>4;  ci = k&15;  cf = lane&15
//   delta = 2c + local_delta  (delta 125 is zero pad; 63 chunks cover 125)
// ---------------------------------------------------------------------------
__global__ void wc_pack_kernel(const float* __restrict__ W1, const float* __restrict__ W2,
                               __hip_bfloat16* __restrict__ WcB) {
    int blk = blockIdx.x;            // cls*63 + c
    int cls = blk / 63, c = blk % 63;
    int t = threadIdx.x;             // 512 = 64 lanes * 8 j
    int l = t >> 3, j = t & 7;
    int k = (l >> 4) * 8 + j;
    int ld = k >> 4, ci = k & 15, cf = l & 15;
    int delta = 2 * c + ld;
    float acc = 0.f;
    if (delta < 125) {
        int sz = delta / 25, sy = (delta / 5) % 5, sx = delta % 5;
        int cz = cls / 9, cy = (cls / 3) % 3, cx = cls % 3;
        for (int k1z = 0; k1z < 3; ++k1z) {
            int k2z = sz - k1z;
            if (k2z < 0 || k2z > 2) continue;
            if ((cz == 0 && k2z == 0) || (cz == 2 && k2z == 2)) continue;
            for (int k1y = 0; k1y < 3; ++k1y) {
                int k2y = sy - k1y;
                if (k2y < 0 || k2y > 2) continue;
                if ((cy == 0 && k2y == 0) || (cy == 2 && k2y == 2)) continue;
                for (int k1x = 0; k1x < 3; ++k1x) {
                    int k2x = sx - k1x;
                    if (k2x < 0 || k2x > 2) continue;
                    if ((cx == 0 && k2x == 0) || (cx == 2 && k2x == 2)) continue;
                    const float* w1 = W1 + ((k1z*3 + k1y)*3 + k1x) * (NCIN*NCOUT) + ci * NCOUT;
                    const float* w2 = W2 + ((k2z*3 + k2y)*3 + k2x) * (NCOUT*NCIN) + cf;
                    #pragma unroll
                    for (int cm = 0; cm < NCOUT; ++cm)
                        acc = fmaf(w1[cm], w2[cm * NCIN], acc);
                }
            }
        }
    }
    WcB[(size_t)blk * 512 + t] = __float2bfloat16(acc);
}

// ---------------------------------------------------------------------------
// Scatter features into padded bf16 dense grid; thread with c==0 also counts
// its voxel into the (tile,cls) histogram.
// ---------------------------------------------------------------------------
__global__ void scatter_count_kernel(const float* __restrict__ feats,
                                     const int* __restrict__ coors,
                                     __hip_bfloat16* __restrict__ dense,
                                     unsigned int* __restrict__ offs) {
    int t = blockIdx.x * blockDim.x + threadIdx.x;
    if (t >= NVOX * NCIN) return;
    int v = t >> 4, c = t & 15;
    int b = coors[v*4+0], z = coors[v*4+1], y = coors[v*4+2], x = coors[v*4+3];
    dense[vox_off(b, z, y, x) + c] = __float2bfloat16(feats[t]);
    if (c == 0) {
        int key = tile_of(b, z, y, x) * 27 + cls_of(z, y, x);
        atomicAdd(&offs[key], 1u);
    }
}

// Exclusive scan over NKEY counts (in place), duplicate into cur, sentinel.
__global__ void scan_kernel(unsigned int* __restrict__ offs, unsigned int* __restrict__ cur) {
    __shared__ unsigned int part[1024];
    __shared__ unsigned int total;
    int t = threadIdx.x;
    const int CH = NKEY / 1024;          // 54 exact
    int s = t * CH, e = s + CH;
    unsigned int sum = 0;
    for (int i = s; i < e; ++i) sum += offs[i];
    part[t] = sum;
    __syncthreads();
    if (t == 0) {
        unsigned int run = 0;
        for (int i = 0; i < 1024; ++i) { unsigned int cc = part[i]; part[i] = run; run += cc; }
        total = run;
    }
    __syncthreads();
    unsigned int run = part[t];
    for (int i = s; i < e; ++i) {
        unsigned int cc = offs[i];
        offs[i] = run; cur[i] = run; run += cc;
    }
    if (t == 1023) offs[NKEY] = total;
}

// Scatter voxel ids into CSR buckets.
__global__ void bucket_kernel(const int* __restrict__ coors,
                              unsigned int* __restrict__ cur,
                              unsigned int* __restrict__ list) {
    int v = blockIdx.x * blockDim.x + threadIdx.x;
    if (v >= NVOX) return;
    int b = coors[v*4+0], z = coors[v*4+1], y = coors[v*4+2], x = coors[v*4+3];
    int key = tile_of(b, z, y, x) * 27 + cls_of(z, y, x);
    unsigned int pos = atomicAdd(&cur[key], 1u);
    list[pos] = (unsigned int)v;
}

// ---------------------------------------------------------------------------
// Main gather-GEMM: one block per spatial tile; waves process 16-voxel groups
// (uniform boundary class per group) with 63 MFMA K-chunks each.
// ---------------------------------------------------------------------------
__global__ void __launch_bounds__(256, 4) main_kernel(
        const int* __restrict__ coors, const __hip_bfloat16* __restrict__ dense,
        const __hip_bfloat16* __restrict__ WcB, const unsigned int* __restrict__ offs,
        const unsigned int* __restrict__ list, float* __restrict__ out) {
    __shared__ int lut[128];
    __shared__ unsigned int g_off[48];
    __shared__ unsigned char g_cls[48];
    __shared__ unsigned char g_cnt[48];
    __shared__ int ng_sh;
    int t = threadIdx.x;
    if (t < 128) {
        int d = t, rel = 0;
        if (d < 125) {
            int dz = d / 25, dy = (d / 5) % 5, dx = d % 5;
            rel = (((dz - 2) * PH + (dy - 2)) * PW + (dx - 2)) * NCIN;
        }
        lut[t] = rel;
    }
    int bid = blockIdx.x;
    int tid = (bid & 7) * (NTILES / 8) + (bid >> 3);   // XCD-aware swizzle (2048%8==0)
    if (t == 0) {
        int ng = 0;
        unsigned int base = (unsigned int)tid * 27;
        for (int c = 0; c < 27; ++c) {
            unsigned int s = offs[base + c], e = offs[base + c + 1];
            for (unsigned int o = s; o < e; o += 16) {
                unsigned int left = e - o;
                g_cls[ng] = (unsigned char)c;
                g_off[ng] = o;
                g_cnt[ng] = (unsigned char)(left < 16 ? left : 16);
                ++ng;
            }
        }
        ng_sh = ng;
    }
    __syncthreads();
    int ng = ng_sh;
    int w = t >> 6, lane = t & 63;
    int col = lane & 15;
    int halfsel = (lane >> 4) & 1;
    int dsel = lane >> 5;

    for (int g = w; g < ng; g += 4) {
        int cls = g_cls[g];
        unsigned int off = g_off[g];
        int cnt = g_cnt[g];
        int r = (col < cnt) ? col : (cnt - 1);     // dummy rows duplicate row0 area
        unsigned int v = list[off + r];
        int b = coors[v*4+0], z = coors[v*4+1], y = coors[v*4+2], x = coors[v*4+3];
        int base = (int)vox_off(b, z, y, x) + halfsel * 8;
        const bf16x8* bq = (const bf16x8*)WcB + (size_t)cls * (63 * 64) + lane;
        f32x4 acc = {0.f, 0.f, 0.f, 0.f};
        #pragma unroll 7
        for (int c = 0; c < 63; ++c) {
            int rel = lut[2 * c + dsel];
            bf16x8 a = *(const bf16x8*)(dense + (base + rel));
            bf16x8 bb = bq[(size_t)c * 64];
            acc = __builtin_amdgcn_mfma_f32_16x16x32_bf16(a, bb, acc, 0, 0, 0);
        }
        #pragma unroll
        for (int reg = 0; reg < 4; ++reg) {
            int orow = (lane >> 4) * 4 + reg;
            if (orow < cnt) {
                unsigned int vo = list[off + orow];
                out[(size_t)vo * 16 + col] = acc[reg];
            }
        }
    }
}

extern "C" void kernel_launch(void* const* d_in, const int* in_sizes, int n_in,
                              void* d_out, int out_size, void* d_ws, size_t ws_size,
                              hipStream_t stream) {
    const float* features = (const float*)d_in[0];
    const int*   coors    = (const int*)d_in[1];
    const float* W1       = (const float*)d_in[2];
    const float* W2       = (const float*)d_in[3];
    float* out = (float*)d_out;

    const size_t dense_elems = (size_t)NB * PD * PH * PW * NCIN;
    const size_t dense_bytes = dense_elems * sizeof(__hip_bfloat16);     // 80.3 MB
    char* p = (char*)d_ws;
    __hip_bfloat16* dense = (__hip_bfloat16*)p;
    p += ((dense_bytes + 255) / 256) * 256;
    __hip_bfloat16* WcB = (__hip_bfloat16*)p;                            // 1.74 MB
    p += (((size_t)27 * 63 * 512 * 2 + 255) / 256) * 256;
    unsigned int* offs = (unsigned int*)p;                               // (NKEY+1)*4
    p += (((size_t)(NKEY + 1) * 4 + 255) / 256) * 256;
    unsigned int* cur = (unsigned int*)p;                                // NKEY*4
    p += (((size_t)NKEY * 4 + 255) / 256) * 256;
    unsigned int* list = (unsigned int*)p;                               // NVOX*4

    hipMemsetAsync(dense, 0, dense_bytes, stream);
    hipMemsetAsync(offs, 0, (size_t)(NKEY + 1) * 4, stream);

    wc_pack_kernel<<<27 * 63, 512, 0, stream>>>(W1, W2, WcB);
    scatter_count_kernel<<<(NVOX * NCIN + 255) / 256, 256, 0, stream>>>(features, coors, dense, offs);
    scan_kernel<<<1, 1024, 0, stream>>>(offs, cur);
    bucket_kernel<<<(NVOX + 255) / 256, 256, 0, stream>>>(coors, cur, list);
    main_kernel<<<NTILES, 256, 0, stream>>>(coors, dense, WcB, offs, list, out);
}